// Round 5
// baseline (56172.675 us; speedup 1.0000x reference)
//
#include <hip/hip_runtime.h>
#include <stdint.h>

#define N_NODES 20000
#define E_EDGES 640000
#define F1 256
#define HDIM 256
#define G3 768
#define HEADS 8
#define HC 128
#define DH 16
#define NA 8
#define MS 64

typedef _Float16 h2 __attribute__((ext_vector_type(2)));

__device__ __forceinline__ float fdot2(uint32_t a, uint32_t b, float c) {
#if __has_builtin(__builtin_amdgcn_fdot2)
  return __builtin_amdgcn_fdot2(__builtin_bit_cast(h2, a), __builtin_bit_cast(h2, b), c, false);
#else
  h2 x = __builtin_bit_cast(h2, a), y = __builtin_bit_cast(h2, b);
  return c + (float)x[0] * (float)y[0] + (float)x[1] * (float)y[1];
#endif
}

__device__ __forceinline__ float fexp2(float x) { return __builtin_amdgcn_exp2f(x); }
__device__ __forceinline__ float frcp(float x)  { return __builtin_amdgcn_rcpf(x); }
__device__ __forceinline__ float sigm(float x)  { return frcp(1.f + fexp2(-1.44269504f * x)); }
__device__ __forceinline__ float tanh_(float x) {
  x = fminf(20.f, fmaxf(-20.f, x));
  float t = fexp2(2.88539008f * x);
  return (t - 1.f) * frcp(t + 1.f);
}
__device__ __forceinline__ float leaky(float x) { return (x > 0.f) ? x : 0.2f * x; }
__device__ __forceinline__ unsigned fenc(float f) {
  unsigned u = __float_as_uint(f);
  return (u & 0x80000000u) ? ~u : (u | 0x80000000u);
}
__device__ __forceinline__ float fdec(unsigned u) {
  return __uint_as_float((u & 0x80000000u) ? (u ^ 0x80000000u) : ~u);
}

// ---------------------------------------------------------------- generic GEMM
#define GF_BIAS 1
#define GF_RELU_OUT 2
#define GF_ACC 4
#define GF_RELU_A 8
#define GF_BT 16

template <int FLAGS>
__global__ __launch_bounds__(256) void gemm_k(const float* __restrict__ A,
                                              const float* __restrict__ B,
                                              const float* __restrict__ bias,
                                              float* __restrict__ C,
                                              int M, int K, int P) {
  __shared__ float As[64][68];
  __shared__ float Bs[64][68];
  int colTiles = P >> 6;
  int bx = blockIdx.x % colTiles;
  int by = blockIdx.x / colTiles;
  int row0 = by * 64, col0 = bx * 64;
  int tid = threadIdx.x;
  int tx = tid & 15, ty = tid >> 4;
  float acc[4][4] = {};
  for (int k0 = 0; k0 < K; k0 += 64) {
    {
      int r = tid >> 2, kq = (tid & 3) * 16;
      int gr = row0 + r;
      const float* ap = A + (size_t)gr * K + k0 + kq;
#pragma unroll
      for (int j = 0; j < 4; j++) {
        float4 v = make_float4(0.f, 0.f, 0.f, 0.f);
        if (gr < M) v = *(const float4*)(ap + 4 * j);
        if (FLAGS & GF_RELU_A) {
          v.x = fmaxf(v.x, 0.f); v.y = fmaxf(v.y, 0.f);
          v.z = fmaxf(v.z, 0.f); v.w = fmaxf(v.w, 0.f);
        }
        As[kq + 4 * j + 0][r] = v.x; As[kq + 4 * j + 1][r] = v.y;
        As[kq + 4 * j + 2][r] = v.z; As[kq + 4 * j + 3][r] = v.w;
      }
    }
    if (FLAGS & GF_BT) {
      int n = tid >> 2, kq = (tid & 3) * 16;
      const float* bp = B + (size_t)(col0 + n) * K + k0 + kq;
#pragma unroll
      for (int j = 0; j < 4; j++) {
        float4 v = *(const float4*)(bp + 4 * j);
        Bs[kq + 4 * j + 0][n] = v.x; Bs[kq + 4 * j + 1][n] = v.y;
        Bs[kq + 4 * j + 2][n] = v.z; Bs[kq + 4 * j + 3][n] = v.w;
      }
    } else {
      int kk = tid >> 2, nq = (tid & 3) * 16;
      const float* bp = B + (size_t)(k0 + kk) * P + col0 + nq;
#pragma unroll
      for (int j = 0; j < 4; j++)
        *(float4*)&Bs[kk][nq + 4 * j] = *(const float4*)(bp + 4 * j);
    }
    __syncthreads();
#pragma unroll
    for (int kk = 0; kk < 64; kk++) {
      float4 av = *(const float4*)&As[kk][ty * 4];
      float4 bv = *(const float4*)&Bs[kk][tx * 4];
      float a4[4] = {av.x, av.y, av.z, av.w};
      float b4[4] = {bv.x, bv.y, bv.z, bv.w};
#pragma unroll
      for (int i = 0; i < 4; i++)
#pragma unroll
        for (int j = 0; j < 4; j++) acc[i][j] = fmaf(a4[i], b4[j], acc[i][j]);
    }
    __syncthreads();
  }
#pragma unroll
  for (int i = 0; i < 4; i++) {
    int gr = row0 + ty * 4 + i;
    if (gr >= M) continue;
#pragma unroll
    for (int j = 0; j < 4; j++) {
      int gc = col0 + tx * 4 + j;
      float v = acc[i][j];
      if (FLAGS & GF_BIAS) v += bias[gc];
      if (FLAGS & GF_RELU_OUT) v = fmaxf(v, 0.f);
      size_t o = (size_t)gr * P + gc;
      if (FLAGS & GF_ACC) C[o] += v; else C[o] = v;
    }
  }
}

// ------------------------------------------------- GRU weight repack (fp32 -> f16 pairs)
// v3 layout for 1024-thread scan: thread t (g=t>>2, c=t&3) owns rows {g,256+g,512+g},
// k in [64c,64c+64). 24 uint4 per thread: slot i, comp m -> q=4i+m in [0,96):
// gate a=q>>5, pair p=q&31: row=a*256+g, k=64c+2p. Buffer dword idx = i*4096 + t*4 + m.
__global__ __launch_bounds__(256) void prep_w(const float* __restrict__ Whh,
                                              uint32_t* __restrict__ Wpk) {
  int idx = blockIdx.x * 256 + threadIdx.x;  // dword index
  if (idx >= 24 * 4096) return;
  int i = idx >> 12;
  int rem = idx & 4095;
  int t = rem >> 2, comp = rem & 3;
  int q = 4 * i + comp;
  int g = t >> 2, c = t & 3;
  int a = q >> 5, p = q & 31;
  int row = a * 256 + g;
  int k = 64 * c + 2 * p;
  h2 v = { (_Float16)Whh[row * 256 + k], (_Float16)Whh[row * 256 + k + 1] };
  Wpk[idx] = __builtin_bit_cast(uint32_t, v);
}

// combined bias for the GI GEMM: bih + bhh for r,z rows (folded), bih only for n rows
__global__ __launch_bounds__(256) void prep_b(const float* __restrict__ bih,
                                              const float* __restrict__ bhh,
                                              float* __restrict__ b2) {
  int i = blockIdx.x * 256 + threadIdx.x;
  if (i < G3) b2[i] = bih[i] + (i < 512 ? bhh[i] : 0.f);
}

// ---------------------------------------------------------------- GRU sequential scan v3
// 1024 threads = 256 groups x 4 K-chunks; group g owns rows {g,256+g,512+g}.
// 3 accumulators/thread, 96 fdot2, 24 pinned uint4 weights (96 VGPR, <=128 cap).
// Butterfly = 6 quad shfl_xor (DPP). Redundant blocks keep the GPU out of low DPM;
// only block 0 writes.
#define WD3(i) uint4 W##i = Wp4[(i) * 1024 + tid];
#define PIN(i) asm volatile("" : "+v"(W##i.x), "+v"(W##i.y), "+v"(W##i.z), "+v"(W##i.w));
#define DOT3x4(H, A, B, C2) \
  s0 = fdot2(A.x, H.x, s0); s1 = fdot2(B.x, H.x, s1); s2 = fdot2(C2.x, H.x, s2); \
  s0 = fdot2(A.y, H.y, s0); s1 = fdot2(B.y, H.y, s1); s2 = fdot2(C2.y, H.y, s2); \
  s0 = fdot2(A.z, H.z, s0); s1 = fdot2(B.z, H.z, s1); s2 = fdot2(C2.z, H.z, s2); \
  s0 = fdot2(A.w, H.w, s0); s1 = fdot2(B.w, H.w, s1); s2 = fdot2(C2.w, H.w, s2);

__global__ __launch_bounds__(1024) void gru_scan(const float* __restrict__ GI,
                                                 const uint32_t* __restrict__ Wpk,
                                                 const float* __restrict__ bhh,
                                                 float* __restrict__ Hout) {
  __shared__ __align__(16) uint32_t hb[2][4][36];
  int tid = threadIdx.x;
  int g = tid >> 2, c = tid & 3;
  const uint4* Wp4 = (const uint4*)Wpk;
  WD3(0)  WD3(1)  WD3(2)  WD3(3)  WD3(4)  WD3(5)  WD3(6)  WD3(7)
  WD3(8)  WD3(9)  WD3(10) WD3(11) WD3(12) WD3(13) WD3(14) WD3(15)
  WD3(16) WD3(17) WD3(18) WD3(19) WD3(20) WD3(21) WD3(22) WD3(23)
  PIN(0)  PIN(1)  PIN(2)  PIN(3)  PIN(4)  PIN(5)  PIN(6)  PIN(7)
  PIN(8)  PIN(9)  PIN(10) PIN(11) PIN(12) PIN(13) PIN(14) PIN(15)
  PIN(16) PIN(17) PIN(18) PIN(19) PIN(20) PIN(21) PIN(22) PIN(23)
  for (int i = tid; i < 2 * 4 * 36; i += 1024) ((uint32_t*)hb)[i] = 0;
  bool wr = (blockIdx.x == 0);
  float bh_n = bhh[512 + g];
  float gr = GI[g], gz = GI[256 + g], gn = GI[512 + g];
  float hreg = 0.f;
  __syncthreads();
  int buf = 0;
#pragma unroll 1
  for (int t = 0; t < N_NODES; t++) {
    int tn = (t + 1 < N_NODES) ? t + 1 : t;
    const float* gp = GI + (size_t)tn * G3;
    float pgr = gp[g], pgz = gp[256 + g], pgn = gp[512 + g];
    float s0 = 0.f, s1 = 0.f, s2 = 0.f;
    const uint4* hc4 = (const uint4*)(&hb[buf][c][0]);
    uint4 Ha = hc4[0], Hb = hc4[1];
    DOT3x4(Ha, W0, W8,  W16)  Ha = hc4[2];
    DOT3x4(Hb, W1, W9,  W17)  Hb = hc4[3];
    DOT3x4(Ha, W2, W10, W18)  Ha = hc4[4];
    DOT3x4(Hb, W3, W11, W19)  Hb = hc4[5];
    DOT3x4(Ha, W4, W12, W20)  Ha = hc4[6];
    DOT3x4(Hb, W5, W13, W21)  Hb = hc4[7];
    DOT3x4(Ha, W6, W14, W22)
    DOT3x4(Hb, W7, W15, W23)
    s0 += __shfl_xor(s0, 1, 64); s0 += __shfl_xor(s0, 2, 64);
    s1 += __shfl_xor(s1, 1, 64); s1 += __shfl_xor(s1, 2, 64);
    s2 += __shfl_xor(s2, 1, 64); s2 += __shfl_xor(s2, 2, 64);
    float r = sigm(gr + s0);
    float z = sigm(gz + s1);
    float n = tanh_(gn + r * (s2 + bh_n));
    float hn = (1.f - z) * n + z * hreg;
    hreg = hn;
    if (c == 0) {
      if (wr) Hout[(size_t)t * HDIM + g] = hn;
      int cc = g >> 6, v = g & 63, p = v >> 1, half = g & 1;
      ushort* hw = (ushort*)&hb[buf ^ 1][cc][0];
      hw[2 * p + half] = __builtin_bit_cast(uint16_t, (_Float16)hn);
    }
    gr = pgr; gz = pgz; gn = pgn;
    __syncthreads();
    buf ^= 1;
  }
}

// ---------------------------------------------------------------- GAT pieces
__global__ __launch_bounds__(256) void esed_k(const float* __restrict__ Hg,
                                              const float* __restrict__ a_s,
                                              const float* __restrict__ a_d,
                                              float* __restrict__ es, float* __restrict__ ed) {
  int idx = blockIdx.x * 256 + threadIdx.x;
  if (idx >= N_NODES * HEADS) return;
  int n = idx >> 3, hd = idx & 7;
  const float* hp = Hg + (size_t)n * HC + hd * DH;
  float s = 0, d = 0;
#pragma unroll
  for (int i = 0; i < DH; i++) {
    float h = hp[i];
    s = fmaf(h, a_s[hd * DH + i], s);
    d = fmaf(h, a_d[hd * DH + i], d);
  }
  es[idx] = s; ed[idx] = d;
}

__global__ __launch_bounds__(256) void esmax_k(const float* __restrict__ es,
                                               unsigned* __restrict__ m) {
  int idx = blockIdx.x * 256 + threadIdx.x;
  float v = (idx < N_NODES * HEADS) ? es[idx] : -1e30f;
#pragma unroll
  for (int mask = 32; mask >= 8; mask >>= 1) v = fmaxf(v, __shfl_xor(v, mask, 64));
  if ((threadIdx.x & 63) < 8) atomicMax(&m[threadIdx.x & 7], fenc(v));
}

// ---------------------------------------------------------------- CSR build
__global__ __launch_bounds__(256) void deg_k(const int* __restrict__ ei, int* __restrict__ deg) {
  int e = blockIdx.x * 256 + threadIdx.x;
  if (e >= E_EDGES) return;
  atomicAdd(&deg[ei[E_EDGES + e]], 1);
}

__global__ __launch_bounds__(1024) void scan_k(const int* __restrict__ deg, int* __restrict__ off) {
  __shared__ int wsum[16];
  __shared__ int carry;
  int tid = threadIdx.x, lane = tid & 63, wv = tid >> 6;
  if (tid == 0) carry = 0;
  __syncthreads();
  for (int base = 0; base < N_NODES; base += 1024) {
    int i = base + tid;
    int v = (i < N_NODES) ? deg[i] : 0;
    int s = v;
#pragma unroll
    for (int d = 1; d < 64; d <<= 1) {
      int t = __shfl_up(s, d, 64);
      if (lane >= d) s += t;
    }
    if (lane == 63) wsum[wv] = s;
    __syncthreads();
    if (wv == 0 && lane < 16) {
      int t = wsum[lane];
#pragma unroll
      for (int d = 1; d < 16; d <<= 1) {
        int u = __shfl_up(t, d, 64);
        if (lane >= d) t += u;
      }
      wsum[lane] = t;
    }
    __syncthreads();
    int prev = (wv > 0) ? wsum[wv - 1] : 0;
    int excl = carry + prev + s - v;
    if (i < N_NODES) off[i] = excl;
    int total = wsum[15];
    __syncthreads();
    if (tid == 0) carry += total;
    __syncthreads();
  }
  if (tid == 0) off[N_NODES] = carry;
}

__global__ __launch_bounds__(256) void scatter_k(const int* __restrict__ ei,
                                                 const int* __restrict__ off,
                                                 int* __restrict__ cnt,
                                                 int* __restrict__ csr_src) {
  int e = blockIdx.x * 256 + threadIdx.x;
  if (e >= E_EDGES) return;
  int d = ei[E_EDGES + e];
  int pos = off[d] + atomicAdd(&cnt[d], 1);
  csr_src[pos] = ei[e];
}

// ---------------------------------------------------------------- GAT gather (1 wave / dst)
template <int RELU>
__global__ __launch_bounds__(256) void gather_k(const int* __restrict__ off,
                                                const int* __restrict__ csr_src,
                                                const float* __restrict__ es,
                                                const float* __restrict__ ed,
                                                const unsigned* __restrict__ esm,
                                                const float* __restrict__ Hg,
                                                const float* __restrict__ bias,
                                                float* __restrict__ out) {
  int wv = threadIdx.x >> 6, lane = threadIdx.x & 63;
  int d = blockIdx.x * 4 + wv;
  if (d >= N_NODES) return;
  int hd0 = lane >> 4, hd1 = 4 + (lane >> 4);
  float ed0 = ed[d * 8 + hd0], ed1 = ed[d * 8 + hd1];
  float cb0 = leaky(fdec(esm[hd0]) + ed0);
  float cb1 = leaky(fdec(esm[hd1]) + ed1);
  int e0 = off[d], e1 = off[d + 1];
  float acc0 = 0, acc1 = 0, den0 = 0, den1 = 0;
  for (int i = e0; i < e1; i++) {
    int s = csr_src[i];
    float p0 = fexp2(1.44269504f * (leaky(es[s * 8 + hd0] + ed0) - cb0));
    float p1 = fexp2(1.44269504f * (leaky(es[s * 8 + hd1] + ed1) - cb1));
    float h0 = Hg[(size_t)s * HC + lane];
    float h1 = Hg[(size_t)s * HC + 64 + lane];
    acc0 = fmaf(p0, h0, acc0); acc1 = fmaf(p1, h1, acc1);
    den0 += p0; den1 += p1;
  }
  float o0 = acc0 * frcp(den0 + 1e-16f);
  float o1 = acc1 * frcp(den1 + 1e-16f);
  if (RELU) {
    o0 = fmaxf(o0 + bias[lane], 0.f);
    o1 = fmaxf(o1 + bias[64 + lane], 0.f);
  }
  out[(size_t)d * HC + lane] = o0;
  out[(size_t)d * HC + 64 + lane] = o1;
}

// ---------------------------------------------------------------- output heads
__global__ __launch_bounds__(64) void heads_k(const float* __restrict__ xgb,
                                              const float* __restrict__ bg2,
                                              const float* __restrict__ H2,
                                              const float* __restrict__ Wc, const float* __restrict__ bc,
                                              const float* __restrict__ Wmu, const float* __restrict__ bmu,
                                              const float* __restrict__ Wm, const float* __restrict__ bm,
                                              float* __restrict__ out) {
  int n = blockIdx.x, l = threadIdx.x;
  __shared__ float xg[HC];
  __shared__ float xr[HDIM];
  for (int i = l; i < HC; i += 64) xg[i] = xgb[(size_t)n * HC + i] + bg2[i];
  for (int i = l; i < HDIM; i += 64) xr[i] = fmaxf(H2[(size_t)n * HDIM + i], 0.f);
  __syncthreads();
  float acc = bm[l];
#pragma unroll 8
  for (int k = 0; k < HC; k++) acc = fmaf(xg[k], Wm[k * MS + l], acc);
  out[N_NODES + (size_t)n * MS + l] = tanh_(acc);
  if (l < NA) {
    float a = bmu[l];
    for (int k = 0; k < HDIM; k++) a = fmaf(xr[k], Wmu[k * NA + l], a);
    for (int k = 0; k < HC; k++) a = fmaf(xg[k], Wmu[(HDIM + k) * NA + l], a);
    out[N_NODES + (size_t)N_NODES * MS + (size_t)n * NA + l] = tanh_(a);
  }
  if (l == 0) {
    float a = bc[0];
    for (int k = 0; k < HC; k++) a = fmaf(xg[k], Wc[k], a);
    out[n] = sigm(a);
  }
}

// ---------------------------------------------------------------- launch
extern "C" void kernel_launch(void* const* d_in, const int* in_sizes, int n_in,
                              void* d_out, int out_size, void* d_ws, size_t ws_size,
                              hipStream_t stream) {
  const float* state = (const float*)d_in[0];
  const float* message = (const float*)d_in[1];
  const int* ei = (const int*)d_in[2];
  const float* Wfc1 = (const float*)d_in[3]; const float* bfc1 = (const float*)d_in[4];
  const float* Wfc2 = (const float*)d_in[5]; const float* bfc2 = (const float*)d_in[6];
  const float* Wih0 = (const float*)d_in[7]; const float* Whh0 = (const float*)d_in[8];
  const float* bih0 = (const float*)d_in[9]; const float* bhh0 = (const float*)d_in[10];
  const float* Wih1 = (const float*)d_in[11]; const float* Whh1 = (const float*)d_in[12];
  const float* bih1 = (const float*)d_in[13]; const float* bhh1 = (const float*)d_in[14];
  const float* Wg1 = (const float*)d_in[15]; const float* as1 = (const float*)d_in[16];
  const float* ad1 = (const float*)d_in[17]; const float* bg1 = (const float*)d_in[18];
  const float* Wg2 = (const float*)d_in[19]; const float* as2 = (const float*)d_in[20];
  const float* ad2 = (const float*)d_in[21]; const float* bg2 = (const float*)d_in[22];
  const float* Wc = (const float*)d_in[23]; const float* bc = (const float*)d_in[24];
  const float* Wmu = (const float*)d_in[25]; const float* bmu = (const float*)d_in[26];
  const float* Wm = (const float*)d_in[27]; const float* bm = (const float*)d_in[28];

  float* ws = (float*)d_ws;
  float* GI = ws;                       // [20000 x 768]; dead after scans, region reused:
  float* HGa = ws;                      //   [20000 x 128] gat h
  float* HGb = ws + 2560000;            //   [20000 x 128] aggregation out (layer2)
  float* X2  = ws + 5120000;            //   [20000 x 128] relu(gat1+bg1)
  float* ES  = ws + 7680000;            //   [20000 x 8]
  float* ED  = ws + 7840000;            //   [20000 x 8]
  unsigned* ESM = (unsigned*)(ws + 8160000);  // [8]
  int* DEG = (int*)(ws + 8200000);      //   [20000]
  int* OFF = (int*)(ws + 8230000);      //   [20001]
  int* CNT = (int*)(ws + 8260000);      //   [20000]
  int* CSR = (int*)(ws + 8300000);      //   [640000]
  float* X  = ws + 15360000;            // [20000 x 256], reused as H1
  float* H2 = ws + 20480000;            // [20000 x 256]
  // B2 lives in the H2 region head: H2 is dead during both GI GEMMs and is
  // fully overwritten by scan 1 afterwards. (R4 bug: B2 was inside GI, which
  // the GI GEMM itself writes -> bias clobbered mid-kernel.)
  float* B2  = H2;                      //   [768] combined GI bias
  uint32_t* Wpk = (uint32_t*)(ws + 25600000); // [24*4096 dwords]
  float* out = (float*)d_out;

  int rt = (N_NODES + 63) / 64;  // 313 row tiles

  gemm_k<GF_BIAS | GF_RELU_OUT><<<rt * 4, 256, 0, stream>>>(state, Wfc1, bfc1, X, N_NODES, 64, 256);
  gemm_k<GF_BIAS | GF_RELU_OUT | GF_ACC><<<rt * 4, 256, 0, stream>>>(message, Wfc2, bfc2, X, N_NODES, 64, 256);
  // GRU layer 0
  prep_b<<<3, 256, 0, stream>>>(bih0, bhh0, B2);
  gemm_k<GF_BIAS | GF_BT><<<rt * 12, 256, 0, stream>>>(X, Wih0, B2, GI, N_NODES, 256, G3);
  prep_w<<<384, 256, 0, stream>>>(Whh0, Wpk);
  gru_scan<<<64, 1024, 0, stream>>>(GI, Wpk, bhh0, X);  // H1 overwrites X
  // GRU layer 1
  prep_b<<<3, 256, 0, stream>>>(bih1, bhh1, B2);
  gemm_k<GF_BIAS | GF_BT><<<rt * 12, 256, 0, stream>>>(X, Wih1, B2, GI, N_NODES, 256, G3);
  prep_w<<<384, 256, 0, stream>>>(Whh1, Wpk);
  gru_scan<<<64, 1024, 0, stream>>>(GI, Wpk, bhh1, H2);
  // CSR build
  hipMemsetAsync(DEG, 0, N_NODES * 4, stream);
  hipMemsetAsync(CNT, 0, N_NODES * 4, stream);
  deg_k<<<2500, 256, 0, stream>>>(ei, DEG);
  scan_k<<<1, 1024, 0, stream>>>(DEG, OFF);
  scatter_k<<<2500, 256, 0, stream>>>(ei, OFF, CNT, CSR);
  // GAT layer 1
  gemm_k<GF_RELU_A><<<rt * 2, 256, 0, stream>>>(H2, Wg1, nullptr, HGa, N_NODES, 256, HC);
  esed_k<<<625, 256, 0, stream>>>(HGa, as1, ad1, ES, ED);
  hipMemsetAsync(ESM, 0, 8 * 4, stream);
  esmax_k<<<625, 256, 0, stream>>>(ES, ESM);
  gather_k<1><<<5000, 256, 0, stream>>>(OFF, CSR, ES, ED, ESM, HGa, bg1, X2);
  // GAT layer 2
  gemm_k<0><<<rt * 2, 256, 0, stream>>>(X2, Wg2, nullptr, HGa, N_NODES, HC, HC);
  esed_k<<<625, 256, 0, stream>>>(HGa, as2, ad2, ES, ED);
  hipMemsetAsync(ESM, 0, 8 * 4, stream);
  esmax_k<<<625, 256, 0, stream>>>(ES, ESM);
  gather_k<0><<<5000, 256, 0, stream>>>(OFF, CSR, ES, ED, ESM, HGa, nullptr, HGb);
  // heads
  heads_k<<<N_NODES, 64, 0, stream>>>(HGb, bg2, H2, Wc, bc, Wmu, bmu, Wm, bm, out);
}

// Round 6
// 54769.220 us; speedup vs baseline: 1.0256x; 1.0256x over previous
//
#include <hip/hip_runtime.h>
#include <stdint.h>

#define N_NODES 20000
#define E_EDGES 640000
#define F1 256
#define HDIM 256
#define G3 768
#define HEADS 8
#define HC 128
#define DH 16
#define NA 8
#define MS 64

typedef _Float16 h2 __attribute__((ext_vector_type(2)));

__device__ __forceinline__ float fdot2(uint32_t a, uint32_t b, float c) {
#if __has_builtin(__builtin_amdgcn_fdot2)
  return __builtin_amdgcn_fdot2(__builtin_bit_cast(h2, a), __builtin_bit_cast(h2, b), c, false);
#else
  h2 x = __builtin_bit_cast(h2, a), y = __builtin_bit_cast(h2, b);
  return c + (float)x[0] * (float)y[0] + (float)x[1] * (float)y[1];
#endif
}

__device__ __forceinline__ float fexp2(float x) { return __builtin_amdgcn_exp2f(x); }
__device__ __forceinline__ float frcp(float x)  { return __builtin_amdgcn_rcpf(x); }
__device__ __forceinline__ float sigm(float x)  { return frcp(1.f + fexp2(-1.44269504f * x)); }
__device__ __forceinline__ float tanh_(float x) {
  x = fminf(20.f, fmaxf(-20.f, x));
  float t = fexp2(2.88539008f * x);
  return (t - 1.f) * frcp(t + 1.f);
}
__device__ __forceinline__ float leaky(float x) { return (x > 0.f) ? x : 0.2f * x; }
__device__ __forceinline__ unsigned fenc(float f) {
  unsigned u = __float_as_uint(f);
  return (u & 0x80000000u) ? ~u : (u | 0x80000000u);
}
__device__ __forceinline__ float fdec(unsigned u) {
  return __uint_as_float((u & 0x80000000u) ? (u ^ 0x80000000u) : ~u);
}

// ---------------------------------------------------------------- generic GEMM
#define GF_BIAS 1
#define GF_RELU_OUT 2
#define GF_ACC 4
#define GF_RELU_A 8
#define GF_BT 16

template <int FLAGS>
__global__ __launch_bounds__(256) void gemm_k(const float* __restrict__ A,
                                              const float* __restrict__ B,
                                              const float* __restrict__ bias,
                                              float* __restrict__ C,
                                              int M, int K, int P) {
  __shared__ float As[64][68];
  __shared__ float Bs[64][68];
  int colTiles = P >> 6;
  int bx = blockIdx.x % colTiles;
  int by = blockIdx.x / colTiles;
  int row0 = by * 64, col0 = bx * 64;
  int tid = threadIdx.x;
  int tx = tid & 15, ty = tid >> 4;
  float acc[4][4] = {};
  for (int k0 = 0; k0 < K; k0 += 64) {
    {
      int r = tid >> 2, kq = (tid & 3) * 16;
      int gr = row0 + r;
      const float* ap = A + (size_t)gr * K + k0 + kq;
#pragma unroll
      for (int j = 0; j < 4; j++) {
        float4 v = make_float4(0.f, 0.f, 0.f, 0.f);
        if (gr < M) v = *(const float4*)(ap + 4 * j);
        if (FLAGS & GF_RELU_A) {
          v.x = fmaxf(v.x, 0.f); v.y = fmaxf(v.y, 0.f);
          v.z = fmaxf(v.z, 0.f); v.w = fmaxf(v.w, 0.f);
        }
        As[kq + 4 * j + 0][r] = v.x; As[kq + 4 * j + 1][r] = v.y;
        As[kq + 4 * j + 2][r] = v.z; As[kq + 4 * j + 3][r] = v.w;
      }
    }
    if (FLAGS & GF_BT) {
      int n = tid >> 2, kq = (tid & 3) * 16;
      const float* bp = B + (size_t)(col0 + n) * K + k0 + kq;
#pragma unroll
      for (int j = 0; j < 4; j++) {
        float4 v = *(const float4*)(bp + 4 * j);
        Bs[kq + 4 * j + 0][n] = v.x; Bs[kq + 4 * j + 1][n] = v.y;
        Bs[kq + 4 * j + 2][n] = v.z; Bs[kq + 4 * j + 3][n] = v.w;
      }
    } else {
      int kk = tid >> 2, nq = (tid & 3) * 16;
      const float* bp = B + (size_t)(k0 + kk) * P + col0 + nq;
#pragma unroll
      for (int j = 0; j < 4; j++)
        *(float4*)&Bs[kk][nq + 4 * j] = *(const float4*)(bp + 4 * j);
    }
    __syncthreads();
#pragma unroll
    for (int kk = 0; kk < 64; kk++) {
      float4 av = *(const float4*)&As[kk][ty * 4];
      float4 bv = *(const float4*)&Bs[kk][tx * 4];
      float a4[4] = {av.x, av.y, av.z, av.w};
      float b4[4] = {bv.x, bv.y, bv.z, bv.w};
#pragma unroll
      for (int i = 0; i < 4; i++)
#pragma unroll
        for (int j = 0; j < 4; j++) acc[i][j] = fmaf(a4[i], b4[j], acc[i][j]);
    }
    __syncthreads();
  }
#pragma unroll
  for (int i = 0; i < 4; i++) {
    int gr = row0 + ty * 4 + i;
    if (gr >= M) continue;
#pragma unroll
    for (int j = 0; j < 4; j++) {
      int gc = col0 + tx * 4 + j;
      float v = acc[i][j];
      if (FLAGS & GF_BIAS) v += bias[gc];
      if (FLAGS & GF_RELU_OUT) v = fmaxf(v, 0.f);
      size_t o = (size_t)gr * P + gc;
      if (FLAGS & GF_ACC) C[o] += v; else C[o] = v;
    }
  }
}

// ------------------------------------------------- GRU weight repack (fp32 -> f16 pairs)
// v3 layout for 1024-thread scan: thread t (g=t>>2, c=t&3) owns rows {g,256+g,512+g},
// k in [64c,64c+64). 24 uint4 per thread: slot i, comp m -> q=4i+m in [0,96):
// gate a=q>>5, pair p=q&31: row=a*256+g, k=64c+2p. Buffer dword idx = i*4096 + t*4 + m.
__global__ __launch_bounds__(256) void prep_w(const float* __restrict__ Whh,
                                              uint32_t* __restrict__ Wpk) {
  int idx = blockIdx.x * 256 + threadIdx.x;  // dword index
  if (idx >= 24 * 4096) return;
  int i = idx >> 12;
  int rem = idx & 4095;
  int t = rem >> 2, comp = rem & 3;
  int q = 4 * i + comp;
  int g = t >> 2, c = t & 3;
  int a = q >> 5, p = q & 31;
  int row = a * 256 + g;
  int k = 64 * c + 2 * p;
  h2 v = { (_Float16)Whh[row * 256 + k], (_Float16)Whh[row * 256 + k + 1] };
  Wpk[idx] = __builtin_bit_cast(uint32_t, v);
}

// combined bias for the GI GEMM: bih + bhh for r,z rows (folded), bih only for n rows
__global__ __launch_bounds__(256) void prep_b(const float* __restrict__ bih,
                                              const float* __restrict__ bhh,
                                              float* __restrict__ b2) {
  int i = blockIdx.x * 256 + threadIdx.x;
  if (i < G3) b2[i] = bih[i] + (i < 512 ? bhh[i] : 0.f);
}

// ---------------------------------------------------------------- GRU sequential scan v3b
// 1024 threads = 256 groups x 4 K-chunks; group g owns rows {g,256+g,512+g}.
// __launch_bounds__(1024, 4): EXACTLY one block/CU -> 128-VGPR cap. (R5 failure:
// no 2nd arg -> compiler targeted 8 waves/EU -> 64-VGPR cap -> pinned weights
// spilled to L2-resident scratch -> scan was L2-BW-bound at ~3160 cyc/step.)
// 24 pinned uint4 weights (96 VGPR) + ~26 others ~= 122 < 128.
#define WD3(i) uint4 W##i = Wp4[(i) * 1024 + tid];
#define PIN(i) asm volatile("" : "+v"(W##i.x), "+v"(W##i.y), "+v"(W##i.z), "+v"(W##i.w));
#define DOT3x4(H, A, B, C2) \
  s0 = fdot2(A.x, H.x, s0); s1 = fdot2(B.x, H.x, s1); s2 = fdot2(C2.x, H.x, s2); \
  s0 = fdot2(A.y, H.y, s0); s1 = fdot2(B.y, H.y, s1); s2 = fdot2(C2.y, H.y, s2); \
  s0 = fdot2(A.z, H.z, s0); s1 = fdot2(B.z, H.z, s1); s2 = fdot2(C2.z, H.z, s2); \
  s0 = fdot2(A.w, H.w, s0); s1 = fdot2(B.w, H.w, s1); s2 = fdot2(C2.w, H.w, s2);

__global__ __launch_bounds__(1024, 4) void gru_scan(const float* __restrict__ GI,
                                                    const uint32_t* __restrict__ Wpk,
                                                    const float* __restrict__ bhh,
                                                    float* __restrict__ Hout) {
  __shared__ __align__(16) uint32_t hb[2][4][36];
  int tid = threadIdx.x;
  int g = tid >> 2, c = tid & 3;
  const uint4* Wp4 = (const uint4*)Wpk;
  WD3(0)  WD3(1)  WD3(2)  WD3(3)  WD3(4)  WD3(5)  WD3(6)  WD3(7)
  WD3(8)  WD3(9)  WD3(10) WD3(11) WD3(12) WD3(13) WD3(14) WD3(15)
  WD3(16) WD3(17) WD3(18) WD3(19) WD3(20) WD3(21) WD3(22) WD3(23)
  PIN(0)  PIN(1)  PIN(2)  PIN(3)  PIN(4)  PIN(5)  PIN(6)  PIN(7)
  PIN(8)  PIN(9)  PIN(10) PIN(11) PIN(12) PIN(13) PIN(14) PIN(15)
  PIN(16) PIN(17) PIN(18) PIN(19) PIN(20) PIN(21) PIN(22) PIN(23)
  for (int i = tid; i < 2 * 4 * 36; i += 1024) ((uint32_t*)hb)[i] = 0;
  bool wr = (blockIdx.x == 0);
  float bh_n = bhh[512 + g];
  float hreg = 0.f;
  __syncthreads();
  int buf = 0;
#pragma unroll 1
  for (int t = 0; t < N_NODES; t++) {
    // issue this step's gi loads first; ~64 dot instrs below hide the latency
    const float* gp = GI + (size_t)t * G3;
    float gr = gp[g], gz = gp[256 + g], gn = gp[512 + g];
    float s0 = 0.f, s1 = 0.f, s2 = 0.f;
    const uint4* hc4 = (const uint4*)(&hb[buf][c][0]);
    uint4 Ha = hc4[0], Hb = hc4[1];
    DOT3x4(Ha, W0, W8,  W16)  Ha = hc4[2];
    DOT3x4(Hb, W1, W9,  W17)  Hb = hc4[3];
    DOT3x4(Ha, W2, W10, W18)  Ha = hc4[4];
    DOT3x4(Hb, W3, W11, W19)  Hb = hc4[5];
    DOT3x4(Ha, W4, W12, W20)  Ha = hc4[6];
    DOT3x4(Hb, W5, W13, W21)  Hb = hc4[7];
    DOT3x4(Ha, W6, W14, W22)
    DOT3x4(Hb, W7, W15, W23)
    s0 += __shfl_xor(s0, 1, 64); s0 += __shfl_xor(s0, 2, 64);
    s1 += __shfl_xor(s1, 1, 64); s1 += __shfl_xor(s1, 2, 64);
    s2 += __shfl_xor(s2, 1, 64); s2 += __shfl_xor(s2, 2, 64);
    float r = sigm(gr + s0);
    float z = sigm(gz + s1);
    float n = tanh_(gn + r * (s2 + bh_n));
    float hn = (1.f - z) * n + z * hreg;
    hreg = hn;
    if (c == 0) {
      if (wr) Hout[(size_t)t * HDIM + g] = hn;
      int cc = g >> 6, v = g & 63, p = v >> 1, half = g & 1;
      ushort* hw = (ushort*)&hb[buf ^ 1][cc][0];
      hw[2 * p + half] = __builtin_bit_cast(uint16_t, (_Float16)hn);
    }
    __syncthreads();
    buf ^= 1;
  }
}

// ---------------------------------------------------------------- GAT pieces
__global__ __launch_bounds__(256) void esed_k(const float* __restrict__ Hg,
                                              const float* __restrict__ a_s,
                                              const float* __restrict__ a_d,
                                              float* __restrict__ es, float* __restrict__ ed) {
  int idx = blockIdx.x * 256 + threadIdx.x;
  if (idx >= N_NODES * HEADS) return;
  int n = idx >> 3, hd = idx & 7;
  const float* hp = Hg + (size_t)n * HC + hd * DH;
  float s = 0, d = 0;
#pragma unroll
  for (int i = 0; i < DH; i++) {
    float h = hp[i];
    s = fmaf(h, a_s[hd * DH + i], s);
    d = fmaf(h, a_d[hd * DH + i], d);
  }
  es[idx] = s; ed[idx] = d;
}

__global__ __launch_bounds__(256) void esmax_k(const float* __restrict__ es,
                                               unsigned* __restrict__ m) {
  int idx = blockIdx.x * 256 + threadIdx.x;
  float v = (idx < N_NODES * HEADS) ? es[idx] : -1e30f;
#pragma unroll
  for (int mask = 32; mask >= 8; mask >>= 1) v = fmaxf(v, __shfl_xor(v, mask, 64));
  if ((threadIdx.x & 63) < 8) atomicMax(&m[threadIdx.x & 7], fenc(v));
}

// ---------------------------------------------------------------- CSR build
__global__ __launch_bounds__(256) void deg_k(const int* __restrict__ ei, int* __restrict__ deg) {
  int e = blockIdx.x * 256 + threadIdx.x;
  if (e >= E_EDGES) return;
  atomicAdd(&deg[ei[E_EDGES + e]], 1);
}

__global__ __launch_bounds__(1024) void scan_k(const int* __restrict__ deg, int* __restrict__ off) {
  __shared__ int wsum[16];
  __shared__ int carry;
  int tid = threadIdx.x, lane = tid & 63, wv = tid >> 6;
  if (tid == 0) carry = 0;
  __syncthreads();
  for (int base = 0; base < N_NODES; base += 1024) {
    int i = base + tid;
    int v = (i < N_NODES) ? deg[i] : 0;
    int s = v;
#pragma unroll
    for (int d = 1; d < 64; d <<= 1) {
      int t = __shfl_up(s, d, 64);
      if (lane >= d) s += t;
    }
    if (lane == 63) wsum[wv] = s;
    __syncthreads();
    if (wv == 0 && lane < 16) {
      int t = wsum[lane];
#pragma unroll
      for (int d = 1; d < 16; d <<= 1) {
        int u = __shfl_up(t, d, 64);
        if (lane >= d) t += u;
      }
      wsum[lane] = t;
    }
    __syncthreads();
    int prev = (wv > 0) ? wsum[wv - 1] : 0;
    int excl = carry + prev + s - v;
    if (i < N_NODES) off[i] = excl;
    int total = wsum[15];
    __syncthreads();
    if (tid == 0) carry += total;
    __syncthreads();
  }
  if (tid == 0) off[N_NODES] = carry;
}

__global__ __launch_bounds__(256) void scatter_k(const int* __restrict__ ei,
                                                 const int* __restrict__ off,
                                                 int* __restrict__ cnt,
                                                 int* __restrict__ csr_src) {
  int e = blockIdx.x * 256 + threadIdx.x;
  if (e >= E_EDGES) return;
  int d = ei[E_EDGES + e];
  int pos = off[d] + atomicAdd(&cnt[d], 1);
  csr_src[pos] = ei[e];
}

// ---------------------------------------------------------------- GAT gather (1 wave / dst)
template <int RELU>
__global__ __launch_bounds__(256) void gather_k(const int* __restrict__ off,
                                                const int* __restrict__ csr_src,
                                                const float* __restrict__ es,
                                                const float* __restrict__ ed,
                                                const unsigned* __restrict__ esm,
                                                const float* __restrict__ Hg,
                                                const float* __restrict__ bias,
                                                float* __restrict__ out) {
  int wv = threadIdx.x >> 6, lane = threadIdx.x & 63;
  int d = blockIdx.x * 4 + wv;
  if (d >= N_NODES) return;
  int hd0 = lane >> 4, hd1 = 4 + (lane >> 4);
  float ed0 = ed[d * 8 + hd0], ed1 = ed[d * 8 + hd1];
  float cb0 = leaky(fdec(esm[hd0]) + ed0);
  float cb1 = leaky(fdec(esm[hd1]) + ed1);
  int e0 = off[d], e1 = off[d + 1];
  float acc0 = 0, acc1 = 0, den0 = 0, den1 = 0;
  for (int i = e0; i < e1; i++) {
    int s = csr_src[i];
    float p0 = fexp2(1.44269504f * (leaky(es[s * 8 + hd0] + ed0) - cb0));
    float p1 = fexp2(1.44269504f * (leaky(es[s * 8 + hd1] + ed1) - cb1));
    float h0 = Hg[(size_t)s * HC + lane];
    float h1 = Hg[(size_t)s * HC + 64 + lane];
    acc0 = fmaf(p0, h0, acc0); acc1 = fmaf(p1, h1, acc1);
    den0 += p0; den1 += p1;
  }
  float o0 = acc0 * frcp(den0 + 1e-16f);
  float o1 = acc1 * frcp(den1 + 1e-16f);
  if (RELU) {
    o0 = fmaxf(o0 + bias[lane], 0.f);
    o1 = fmaxf(o1 + bias[64 + lane], 0.f);
  }
  out[(size_t)d * HC + lane] = o0;
  out[(size_t)d * HC + 64 + lane] = o1;
}

// ---------------------------------------------------------------- output heads
__global__ __launch_bounds__(64) void heads_k(const float* __restrict__ xgb,
                                              const float* __restrict__ bg2,
                                              const float* __restrict__ H2,
                                              const float* __restrict__ Wc, const float* __restrict__ bc,
                                              const float* __restrict__ Wmu, const float* __restrict__ bmu,
                                              const float* __restrict__ Wm, const float* __restrict__ bm,
                                              float* __restrict__ out) {
  int n = blockIdx.x, l = threadIdx.x;
  __shared__ float xg[HC];
  __shared__ float xr[HDIM];
  for (int i = l; i < HC; i += 64) xg[i] = xgb[(size_t)n * HC + i] + bg2[i];
  for (int i = l; i < HDIM; i += 64) xr[i] = fmaxf(H2[(size_t)n * HDIM + i], 0.f);
  __syncthreads();
  float acc = bm[l];
#pragma unroll 8
  for (int k = 0; k < HC; k++) acc = fmaf(xg[k], Wm[k * MS + l], acc);
  out[N_NODES + (size_t)n * MS + l] = tanh_(acc);
  if (l < NA) {
    float a = bmu[l];
    for (int k = 0; k < HDIM; k++) a = fmaf(xr[k], Wmu[k * NA + l], a);
    for (int k = 0; k < HC; k++) a = fmaf(xg[k], Wmu[(HDIM + k) * NA + l], a);
    out[N_NODES + (size_t)N_NODES * MS + (size_t)n * NA + l] = tanh_(a);
  }
  if (l == 0) {
    float a = bc[0];
    for (int k = 0; k < HC; k++) a = fmaf(xg[k], Wc[k], a);
    out[n] = sigm(a);
  }
}

// ---------------------------------------------------------------- launch
extern "C" void kernel_launch(void* const* d_in, const int* in_sizes, int n_in,
                              void* d_out, int out_size, void* d_ws, size_t ws_size,
                              hipStream_t stream) {
  const float* state = (const float*)d_in[0];
  const float* message = (const float*)d_in[1];
  const int* ei = (const int*)d_in[2];
  const float* Wfc1 = (const float*)d_in[3]; const float* bfc1 = (const float*)d_in[4];
  const float* Wfc2 = (const float*)d_in[5]; const float* bfc2 = (const float*)d_in[6];
  const float* Wih0 = (const float*)d_in[7]; const float* Whh0 = (const float*)d_in[8];
  const float* bih0 = (const float*)d_in[9]; const float* bhh0 = (const float*)d_in[10];
  const float* Wih1 = (const float*)d_in[11]; const float* Whh1 = (const float*)d_in[12];
  const float* bih1 = (const float*)d_in[13]; const float* bhh1 = (const float*)d_in[14];
  const float* Wg1 = (const float*)d_in[15]; const float* as1 = (const float*)d_in[16];
  const float* ad1 = (const float*)d_in[17]; const float* bg1 = (const float*)d_in[18];
  const float* Wg2 = (const float*)d_in[19]; const float* as2 = (const float*)d_in[20];
  const float* ad2 = (const float*)d_in[21]; const float* bg2 = (const float*)d_in[22];
  const float* Wc = (const float*)d_in[23]; const float* bc = (const float*)d_in[24];
  const float* Wmu = (const float*)d_in[25]; const float* bmu = (const float*)d_in[26];
  const float* Wm = (const float*)d_in[27]; const float* bm = (const float*)d_in[28];

  float* ws = (float*)d_ws;
  float* GI = ws;                       // [20000 x 768]; dead after scans, region reused:
  float* HGa = ws;                      //   [20000 x 128] gat h
  float* HGb = ws + 2560000;            //   [20000 x 128] aggregation out (layer2)
  float* X2  = ws + 5120000;            //   [20000 x 128] relu(gat1+bg1)
  float* ES  = ws + 7680000;            //   [20000 x 8]
  float* ED  = ws + 7840000;            //   [20000 x 8]
  unsigned* ESM = (unsigned*)(ws + 8160000);  // [8]
  int* DEG = (int*)(ws + 8200000);      //   [20000]
  int* OFF = (int*)(ws + 8230000);      //   [20001]
  int* CNT = (int*)(ws + 8260000);      //   [20000]
  int* CSR = (int*)(ws + 8300000);      //   [640000]
  float* X  = ws + 15360000;            // [20000 x 256], reused as H1
  float* H2 = ws + 20480000;            // [20000 x 256]
  // B2 in the H2 region head: dead during both GI GEMMs, overwritten by scan 1.
  float* B2  = H2;                      //   [768] combined GI bias
  uint32_t* Wpk = (uint32_t*)(ws + 25600000); // [24*4096 dwords]
  float* out = (float*)d_out;

  int rt = (N_NODES + 63) / 64;  // 313 row tiles

  gemm_k<GF_BIAS | GF_RELU_OUT><<<rt * 4, 256, 0, stream>>>(state, Wfc1, bfc1, X, N_NODES, 64, 256);
  gemm_k<GF_BIAS | GF_RELU_OUT | GF_ACC><<<rt * 4, 256, 0, stream>>>(message, Wfc2, bfc2, X, N_NODES, 64, 256);
  // GRU layer 0
  prep_b<<<3, 256, 0, stream>>>(bih0, bhh0, B2);
  gemm_k<GF_BIAS | GF_BT><<<rt * 12, 256, 0, stream>>>(X, Wih0, B2, GI, N_NODES, 256, G3);
  prep_w<<<384, 256, 0, stream>>>(Whh0, Wpk);
  gru_scan<<<64, 1024, 0, stream>>>(GI, Wpk, bhh0, X);  // H1 overwrites X
  // GRU layer 1
  prep_b<<<3, 256, 0, stream>>>(bih1, bhh1, B2);
  gemm_k<GF_BIAS | GF_BT><<<rt * 12, 256, 0, stream>>>(X, Wih1, B2, GI, N_NODES, 256, G3);
  prep_w<<<384, 256, 0, stream>>>(Whh1, Wpk);
  gru_scan<<<64, 1024, 0, stream>>>(GI, Wpk, bhh1, H2);
  // CSR build
  hipMemsetAsync(DEG, 0, N_NODES * 4, stream);
  hipMemsetAsync(CNT, 0, N_NODES * 4, stream);
  deg_k<<<2500, 256, 0, stream>>>(ei, DEG);
  scan_k<<<1, 1024, 0, stream>>>(DEG, OFF);
  scatter_k<<<2500, 256, 0, stream>>>(ei, OFF, CNT, CSR);
  // GAT layer 1
  gemm_k<GF_RELU_A><<<rt * 2, 256, 0, stream>>>(H2, Wg1, nullptr, HGa, N_NODES, 256, HC);
  esed_k<<<625, 256, 0, stream>>>(HGa, as1, ad1, ES, ED);
  hipMemsetAsync(ESM, 0, 8 * 4, stream);
  esmax_k<<<625, 256, 0, stream>>>(ES, ESM);
  gather_k<1><<<5000, 256, 0, stream>>>(OFF, CSR, ES, ED, ESM, HGa, bg1, X2);
  // GAT layer 2
  gemm_k<0><<<rt * 2, 256, 0, stream>>>(X2, Wg2, nullptr, HGa, N_NODES, HC, HC);
  esed_k<<<625, 256, 0, stream>>>(HGa, as2, ad2, ES, ED);
  hipMemsetAsync(ESM, 0, 8 * 4, stream);
  esmax_k<<<625, 256, 0, stream>>>(ES, ESM);
  gather_k<0><<<5000, 256, 0, stream>>>(OFF, CSR, ES, ED, ESM, HGa, nullptr, HGb);
  // heads
  heads_k<<<N_NODES, 64, 0, stream>>>(HGb, bg2, H2, Wc, bc, Wmu, bmu, Wm, bm, out);
}

// Round 7
// 54736.438 us; speedup vs baseline: 1.0262x; 1.0006x over previous
//
#include <hip/hip_runtime.h>
#include <stdint.h>

#define N_NODES 20000
#define E_EDGES 640000
#define F1 256
#define HDIM 256
#define G3 768
#define HEADS 8
#define HC 128
#define DH 16
#define NA 8
#define MS 64

typedef _Float16 h2 __attribute__((ext_vector_type(2)));

__device__ __forceinline__ float fdot2(uint32_t a, uint32_t b, float c) {
#if __has_builtin(__builtin_amdgcn_fdot2)
  return __builtin_amdgcn_fdot2(__builtin_bit_cast(h2, a), __builtin_bit_cast(h2, b), c, false);
#else
  h2 x = __builtin_bit_cast(h2, a), y = __builtin_bit_cast(h2, b);
  return c + (float)x[0] * (float)y[0] + (float)x[1] * (float)y[1];
#endif
}

__device__ __forceinline__ float fexp2(float x) { return __builtin_amdgcn_exp2f(x); }
__device__ __forceinline__ float frcp(float x)  { return __builtin_amdgcn_rcpf(x); }
__device__ __forceinline__ float sigm(float x)  { return frcp(1.f + fexp2(-1.44269504f * x)); }
__device__ __forceinline__ float tanh_(float x) {
  x = fminf(20.f, fmaxf(-20.f, x));
  float t = fexp2(2.88539008f * x);
  return (t - 1.f) * frcp(t + 1.f);
}
__device__ __forceinline__ float leaky(float x) { return (x > 0.f) ? x : 0.2f * x; }
__device__ __forceinline__ unsigned fenc(float f) {
  unsigned u = __float_as_uint(f);
  return (u & 0x80000000u) ? ~u : (u | 0x80000000u);
}
__device__ __forceinline__ float fdec(unsigned u) {
  return __uint_as_float((u & 0x80000000u) ? (u ^ 0x80000000u) : ~u);
}

// ---------------------------------------------------------------- generic GEMM
#define GF_BIAS 1
#define GF_RELU_OUT 2
#define GF_ACC 4
#define GF_RELU_A 8
#define GF_BT 16

template <int FLAGS>
__global__ __launch_bounds__(256) void gemm_k(const float* __restrict__ A,
                                              const float* __restrict__ B,
                                              const float* __restrict__ bias,
                                              float* __restrict__ C,
                                              int M, int K, int P) {
  __shared__ float As[64][68];
  __shared__ float Bs[64][68];
  int colTiles = P >> 6;
  int bx = blockIdx.x % colTiles;
  int by = blockIdx.x / colTiles;
  int row0 = by * 64, col0 = bx * 64;
  int tid = threadIdx.x;
  int tx = tid & 15, ty = tid >> 4;
  float acc[4][4] = {};
  for (int k0 = 0; k0 < K; k0 += 64) {
    {
      int r = tid >> 2, kq = (tid & 3) * 16;
      int gr = row0 + r;
      const float* ap = A + (size_t)gr * K + k0 + kq;
#pragma unroll
      for (int j = 0; j < 4; j++) {
        float4 v = make_float4(0.f, 0.f, 0.f, 0.f);
        if (gr < M) v = *(const float4*)(ap + 4 * j);
        if (FLAGS & GF_RELU_A) {
          v.x = fmaxf(v.x, 0.f); v.y = fmaxf(v.y, 0.f);
          v.z = fmaxf(v.z, 0.f); v.w = fmaxf(v.w, 0.f);
        }
        As[kq + 4 * j + 0][r] = v.x; As[kq + 4 * j + 1][r] = v.y;
        As[kq + 4 * j + 2][r] = v.z; As[kq + 4 * j + 3][r] = v.w;
      }
    }
    if (FLAGS & GF_BT) {
      int n = tid >> 2, kq = (tid & 3) * 16;
      const float* bp = B + (size_t)(col0 + n) * K + k0 + kq;
#pragma unroll
      for (int j = 0; j < 4; j++) {
        float4 v = *(const float4*)(bp + 4 * j);
        Bs[kq + 4 * j + 0][n] = v.x; Bs[kq + 4 * j + 1][n] = v.y;
        Bs[kq + 4 * j + 2][n] = v.z; Bs[kq + 4 * j + 3][n] = v.w;
      }
    } else {
      int kk = tid >> 2, nq = (tid & 3) * 16;
      const float* bp = B + (size_t)(k0 + kk) * P + col0 + nq;
#pragma unroll
      for (int j = 0; j < 4; j++)
        *(float4*)&Bs[kk][nq + 4 * j] = *(const float4*)(bp + 4 * j);
    }
    __syncthreads();
#pragma unroll
    for (int kk = 0; kk < 64; kk++) {
      float4 av = *(const float4*)&As[kk][ty * 4];
      float4 bv = *(const float4*)&Bs[kk][tx * 4];
      float a4[4] = {av.x, av.y, av.z, av.w};
      float b4[4] = {bv.x, bv.y, bv.z, bv.w};
#pragma unroll
      for (int i = 0; i < 4; i++)
#pragma unroll
        for (int j = 0; j < 4; j++) acc[i][j] = fmaf(a4[i], b4[j], acc[i][j]);
    }
    __syncthreads();
  }
#pragma unroll
  for (int i = 0; i < 4; i++) {
    int gr = row0 + ty * 4 + i;
    if (gr >= M) continue;
#pragma unroll
    for (int j = 0; j < 4; j++) {
      int gc = col0 + tx * 4 + j;
      float v = acc[i][j];
      if (FLAGS & GF_BIAS) v += bias[gc];
      if (FLAGS & GF_RELU_OUT) v = fmaxf(v, 0.f);
      size_t o = (size_t)gr * P + gc;
      if (FLAGS & GF_ACC) C[o] += v; else C[o] = v;
    }
  }
}

// ------------------------------------------------- GRU weight repack (fp32 -> f16 pairs)
// v3 layout for 1024-thread scan: thread t (g=t>>2, c=t&3) owns rows {g,256+g,512+g},
// k in [64c,64c+64). 24 uint4 per thread: slot i, comp m -> q=4i+m in [0,96):
// gate a=q>>5, pair p=q&31: row=a*256+g, k=64c+2p. Buffer dword idx = i*4096 + t*4 + m.
__global__ __launch_bounds__(256) void prep_w(const float* __restrict__ Whh,
                                              uint32_t* __restrict__ Wpk) {
  int idx = blockIdx.x * 256 + threadIdx.x;  // dword index
  if (idx >= 24 * 4096) return;
  int i = idx >> 12;
  int rem = idx & 4095;
  int t = rem >> 2, comp = rem & 3;
  int q = 4 * i + comp;
  int g = t >> 2, c = t & 3;
  int a = q >> 5, p = q & 31;
  int row = a * 256 + g;
  int k = 64 * c + 2 * p;
  h2 v = { (_Float16)Whh[row * 256 + k], (_Float16)Whh[row * 256 + k + 1] };
  Wpk[idx] = __builtin_bit_cast(uint32_t, v);
}

// combined bias for the GI GEMM: bih + bhh for r,z rows (folded), bih only for n rows
__global__ __launch_bounds__(256) void prep_b(const float* __restrict__ bih,
                                              const float* __restrict__ bhh,
                                              float* __restrict__ b2) {
  int i = blockIdx.x * 256 + threadIdx.x;
  if (i < G3) b2[i] = bih[i] + (i < 512 ? bhh[i] : 0.f);
}

// ---------------------------------------------------------------- GRU sequential scan v3c
// 1024 threads = 256 groups x 4 K-chunks; group g owns rows {g,256+g,512+g}.
// KEY FIX (R6 post-mortem): __launch_bounds__'s 2nd arg is only a MIN waves/EU
// (VGPR upper bound); the allocator still targets its default 8 waves/EU and
// spills to scratch (R3: cap 256, alloc 116; R6: cap 128, alloc 60).
// amdgpu_waves_per_eu(4,4) pins the occupancy TARGET to 4 waves/EU -> the
// allocator budgets 128 VGPRs and keeps the 96 pinned weight regs resident.
#define WD3(i) uint4 W##i = Wp4[(i) * 1024 + tid];
#define PIN(i) asm volatile("" : "+v"(W##i.x), "+v"(W##i.y), "+v"(W##i.z), "+v"(W##i.w));
#define DOT3x4(H, A, B, C2) \
  s0 = fdot2(A.x, H.x, s0); s1 = fdot2(B.x, H.x, s1); s2 = fdot2(C2.x, H.x, s2); \
  s0 = fdot2(A.y, H.y, s0); s1 = fdot2(B.y, H.y, s1); s2 = fdot2(C2.y, H.y, s2); \
  s0 = fdot2(A.z, H.z, s0); s1 = fdot2(B.z, H.z, s1); s2 = fdot2(C2.z, H.z, s2); \
  s0 = fdot2(A.w, H.w, s0); s1 = fdot2(B.w, H.w, s1); s2 = fdot2(C2.w, H.w, s2);

__global__ __launch_bounds__(1024)
__attribute__((amdgpu_waves_per_eu(4, 4)))
void gru_scan(const float* __restrict__ GI,
              const uint32_t* __restrict__ Wpk,
              const float* __restrict__ bhh,
              float* __restrict__ Hout) {
  __shared__ __align__(16) uint32_t hb[2][4][36];
  int tid = threadIdx.x;
  int g = tid >> 2, c = tid & 3;
  const uint4* Wp4 = (const uint4*)Wpk;
  WD3(0)  WD3(1)  WD3(2)  WD3(3)  WD3(4)  WD3(5)  WD3(6)  WD3(7)
  WD3(8)  WD3(9)  WD3(10) WD3(11) WD3(12) WD3(13) WD3(14) WD3(15)
  WD3(16) WD3(17) WD3(18) WD3(19) WD3(20) WD3(21) WD3(22) WD3(23)
  PIN(0)  PIN(1)  PIN(2)  PIN(3)  PIN(4)  PIN(5)  PIN(6)  PIN(7)
  PIN(8)  PIN(9)  PIN(10) PIN(11) PIN(12) PIN(13) PIN(14) PIN(15)
  PIN(16) PIN(17) PIN(18) PIN(19) PIN(20) PIN(21) PIN(22) PIN(23)
  for (int i = tid; i < 2 * 4 * 36; i += 1024) ((uint32_t*)hb)[i] = 0;
  bool wr = (blockIdx.x == 0);
  float bh_n = bhh[512 + g];
  float hreg = 0.f;
  __syncthreads();
  int buf = 0;
#pragma unroll 1
  for (int t = 0; t < N_NODES; t++) {
    // issue this step's gi loads first; ~96 dot instrs below hide the latency
    const float* gp = GI + (size_t)t * G3;
    float gr = gp[g], gz = gp[256 + g], gn = gp[512 + g];
    float s0 = 0.f, s1 = 0.f, s2 = 0.f;
    const uint4* hc4 = (const uint4*)(&hb[buf][c][0]);
    uint4 Ha = hc4[0], Hb = hc4[1];
    DOT3x4(Ha, W0, W8,  W16)  Ha = hc4[2];
    DOT3x4(Hb, W1, W9,  W17)  Hb = hc4[3];
    DOT3x4(Ha, W2, W10, W18)  Ha = hc4[4];
    DOT3x4(Hb, W3, W11, W19)  Hb = hc4[5];
    DOT3x4(Ha, W4, W12, W20)  Ha = hc4[6];
    DOT3x4(Hb, W5, W13, W21)  Hb = hc4[7];
    DOT3x4(Ha, W6, W14, W22)
    DOT3x4(Hb, W7, W15, W23)
    s0 += __shfl_xor(s0, 1, 64); s0 += __shfl_xor(s0, 2, 64);
    s1 += __shfl_xor(s1, 1, 64); s1 += __shfl_xor(s1, 2, 64);
    s2 += __shfl_xor(s2, 1, 64); s2 += __shfl_xor(s2, 2, 64);
    float r = sigm(gr + s0);
    float z = sigm(gz + s1);
    float n = tanh_(gn + r * (s2 + bh_n));
    float hn = (1.f - z) * n + z * hreg;
    hreg = hn;
    if (c == 0) {
      if (wr) Hout[(size_t)t * HDIM + g] = hn;
      int cc = g >> 6, v = g & 63, p = v >> 1, half = g & 1;
      ushort* hw = (ushort*)&hb[buf ^ 1][cc][0];
      hw[2 * p + half] = __builtin_bit_cast(uint16_t, (_Float16)hn);
    }
    __syncthreads();
    buf ^= 1;
  }
}

// ---------------------------------------------------------------- GAT pieces
__global__ __launch_bounds__(256) void esed_k(const float* __restrict__ Hg,
                                              const float* __restrict__ a_s,
                                              const float* __restrict__ a_d,
                                              float* __restrict__ es, float* __restrict__ ed) {
  int idx = blockIdx.x * 256 + threadIdx.x;
  if (idx >= N_NODES * HEADS) return;
  int n = idx >> 3, hd = idx & 7;
  const float* hp = Hg + (size_t)n * HC + hd * DH;
  float s = 0, d = 0;
#pragma unroll
  for (int i = 0; i < DH; i++) {
    float h = hp[i];
    s = fmaf(h, a_s[hd * DH + i], s);
    d = fmaf(h, a_d[hd * DH + i], d);
  }
  es[idx] = s; ed[idx] = d;
}

__global__ __launch_bounds__(256) void esmax_k(const float* __restrict__ es,
                                               unsigned* __restrict__ m) {
  int idx = blockIdx.x * 256 + threadIdx.x;
  float v = (idx < N_NODES * HEADS) ? es[idx] : -1e30f;
#pragma unroll
  for (int mask = 32; mask >= 8; mask >>= 1) v = fmaxf(v, __shfl_xor(v, mask, 64));
  if ((threadIdx.x & 63) < 8) atomicMax(&m[threadIdx.x & 7], fenc(v));
}

// ---------------------------------------------------------------- CSR build
__global__ __launch_bounds__(256) void deg_k(const int* __restrict__ ei, int* __restrict__ deg) {
  int e = blockIdx.x * 256 + threadIdx.x;
  if (e >= E_EDGES) return;
  atomicAdd(&deg[ei[E_EDGES + e]], 1);
}

__global__ __launch_bounds__(1024) void scan_k(const int* __restrict__ deg, int* __restrict__ off) {
  __shared__ int wsum[16];
  __shared__ int carry;
  int tid = threadIdx.x, lane = tid & 63, wv = tid >> 6;
  if (tid == 0) carry = 0;
  __syncthreads();
  for (int base = 0; base < N_NODES; base += 1024) {
    int i = base + tid;
    int v = (i < N_NODES) ? deg[i] : 0;
    int s = v;
#pragma unroll
    for (int d = 1; d < 64; d <<= 1) {
      int t = __shfl_up(s, d, 64);
      if (lane >= d) s += t;
    }
    if (lane == 63) wsum[wv] = s;
    __syncthreads();
    if (wv == 0 && lane < 16) {
      int t = wsum[lane];
#pragma unroll
      for (int d = 1; d < 16; d <<= 1) {
        int u = __shfl_up(t, d, 64);
        if (lane >= d) t += u;
      }
      wsum[lane] = t;
    }
    __syncthreads();
    int prev = (wv > 0) ? wsum[wv - 1] : 0;
    int excl = carry + prev + s - v;
    if (i < N_NODES) off[i] = excl;
    int total = wsum[15];
    __syncthreads();
    if (tid == 0) carry += total;
    __syncthreads();
  }
  if (tid == 0) off[N_NODES] = carry;
}

__global__ __launch_bounds__(256) void scatter_k(const int* __restrict__ ei,
                                                 const int* __restrict__ off,
                                                 int* __restrict__ cnt,
                                                 int* __restrict__ csr_src) {
  int e = blockIdx.x * 256 + threadIdx.x;
  if (e >= E_EDGES) return;
  int d = ei[E_EDGES + e];
  int pos = off[d] + atomicAdd(&cnt[d], 1);
  csr_src[pos] = ei[e];
}

// ---------------------------------------------------------------- GAT gather (1 wave / dst)
template <int RELU>
__global__ __launch_bounds__(256) void gather_k(const int* __restrict__ off,
                                                const int* __restrict__ csr_src,
                                                const float* __restrict__ es,
                                                const float* __restrict__ ed,
                                                const unsigned* __restrict__ esm,
                                                const float* __restrict__ Hg,
                                                const float* __restrict__ bias,
                                                float* __restrict__ out) {
  int wv = threadIdx.x >> 6, lane = threadIdx.x & 63;
  int d = blockIdx.x * 4 + wv;
  if (d >= N_NODES) return;
  int hd0 = lane >> 4, hd1 = 4 + (lane >> 4);
  float ed0 = ed[d * 8 + hd0], ed1 = ed[d * 8 + hd1];
  float cb0 = leaky(fdec(esm[hd0]) + ed0);
  float cb1 = leaky(fdec(esm[hd1]) + ed1);
  int e0 = off[d], e1 = off[d + 1];
  float acc0 = 0, acc1 = 0, den0 = 0, den1 = 0;
  for (int i = e0; i < e1; i++) {
    int s = csr_src[i];
    float p0 = fexp2(1.44269504f * (leaky(es[s * 8 + hd0] + ed0) - cb0));
    float p1 = fexp2(1.44269504f * (leaky(es[s * 8 + hd1] + ed1) - cb1));
    float h0 = Hg[(size_t)s * HC + lane];
    float h1 = Hg[(size_t)s * HC + 64 + lane];
    acc0 = fmaf(p0, h0, acc0); acc1 = fmaf(p1, h1, acc1);
    den0 += p0; den1 += p1;
  }
  float o0 = acc0 * frcp(den0 + 1e-16f);
  float o1 = acc1 * frcp(den1 + 1e-16f);
  if (RELU) {
    o0 = fmaxf(o0 + bias[lane], 0.f);
    o1 = fmaxf(o1 + bias[64 + lane], 0.f);
  }
  out[(size_t)d * HC + lane] = o0;
  out[(size_t)d * HC + 64 + lane] = o1;
}

// ---------------------------------------------------------------- output heads
__global__ __launch_bounds__(64) void heads_k(const float* __restrict__ xgb,
                                              const float* __restrict__ bg2,
                                              const float* __restrict__ H2,
                                              const float* __restrict__ Wc, const float* __restrict__ bc,
                                              const float* __restrict__ Wmu, const float* __restrict__ bmu,
                                              const float* __restrict__ Wm, const float* __restrict__ bm,
                                              float* __restrict__ out) {
  int n = blockIdx.x, l = threadIdx.x;
  __shared__ float xg[HC];
  __shared__ float xr[HDIM];
  for (int i = l; i < HC; i += 64) xg[i] = xgb[(size_t)n * HC + i] + bg2[i];
  for (int i = l; i < HDIM; i += 64) xr[i] = fmaxf(H2[(size_t)n * HDIM + i], 0.f);
  __syncthreads();
  float acc = bm[l];
#pragma unroll 8
  for (int k = 0; k < HC; k++) acc = fmaf(xg[k], Wm[k * MS + l], acc);
  out[N_NODES + (size_t)n * MS + l] = tanh_(acc);
  if (l < NA) {
    float a = bmu[l];
    for (int k = 0; k < HDIM; k++) a = fmaf(xr[k], Wmu[k * NA + l], a);
    for (int k = 0; k < HC; k++) a = fmaf(xg[k], Wmu[(HDIM + k) * NA + l], a);
    out[N_NODES + (size_t)N_NODES * MS + (size_t)n * NA + l] = tanh_(a);
  }
  if (l == 0) {
    float a = bc[0];
    for (int k = 0; k < HC; k++) a = fmaf(xg[k], Wc[k], a);
    out[n] = sigm(a);
  }
}

// ---------------------------------------------------------------- launch
extern "C" void kernel_launch(void* const* d_in, const int* in_sizes, int n_in,
                              void* d_out, int out_size, void* d_ws, size_t ws_size,
                              hipStream_t stream) {
  const float* state = (const float*)d_in[0];
  const float* message = (const float*)d_in[1];
  const int* ei = (const int*)d_in[2];
  const float* Wfc1 = (const float*)d_in[3]; const float* bfc1 = (const float*)d_in[4];
  const float* Wfc2 = (const float*)d_in[5]; const float* bfc2 = (const float*)d_in[6];
  const float* Wih0 = (const float*)d_in[7]; const float* Whh0 = (const float*)d_in[8];
  const float* bih0 = (const float*)d_in[9]; const float* bhh0 = (const float*)d_in[10];
  const float* Wih1 = (const float*)d_in[11]; const float* Whh1 = (const float*)d_in[12];
  const float* bih1 = (const float*)d_in[13]; const float* bhh1 = (const float*)d_in[14];
  const float* Wg1 = (const float*)d_in[15]; const float* as1 = (const float*)d_in[16];
  const float* ad1 = (const float*)d_in[17]; const float* bg1 = (const float*)d_in[18];
  const float* Wg2 = (const float*)d_in[19]; const float* as2 = (const float*)d_in[20];
  const float* ad2 = (const float*)d_in[21]; const float* bg2 = (const float*)d_in[22];
  const float* Wc = (const float*)d_in[23]; const float* bc = (const float*)d_in[24];
  const float* Wmu = (const float*)d_in[25]; const float* bmu = (const float*)d_in[26];
  const float* Wm = (const float*)d_in[27]; const float* bm = (const float*)d_in[28];

  float* ws = (float*)d_ws;
  float* GI = ws;                       // [20000 x 768]; dead after scans, region reused:
  float* HGa = ws;                      //   [20000 x 128] gat h
  float* HGb = ws + 2560000;            //   [20000 x 128] aggregation out (layer2)
  float* X2  = ws + 5120000;            //   [20000 x 128] relu(gat1+bg1)
  float* ES  = ws + 7680000;            //   [20000 x 8]
  float* ED  = ws + 7840000;            //   [20000 x 8]
  unsigned* ESM = (unsigned*)(ws + 8160000);  // [8]
  int* DEG = (int*)(ws + 8200000);      //   [20000]
  int* OFF = (int*)(ws + 8230000);      //   [20001]
  int* CNT = (int*)(ws + 8260000);      //   [20000]
  int* CSR = (int*)(ws + 8300000);      //   [640000]
  float* X  = ws + 15360000;            // [20000 x 256], reused as H1
  float* H2 = ws + 20480000;            // [20000 x 256]
  // B2 in the H2 region head: dead during both GI GEMMs, overwritten by scan 1.
  float* B2  = H2;                      //   [768] combined GI bias
  uint32_t* Wpk = (uint32_t*)(ws + 25600000); // [24*4096 dwords]
  float* out = (float*)d_out;

  int rt = (N_NODES + 63) / 64;  // 313 row tiles

  gemm_k<GF_BIAS | GF_RELU_OUT><<<rt * 4, 256, 0, stream>>>(state, Wfc1, bfc1, X, N_NODES, 64, 256);
  gemm_k<GF_BIAS | GF_RELU_OUT | GF_ACC><<<rt * 4, 256, 0, stream>>>(message, Wfc2, bfc2, X, N_NODES, 64, 256);
  // GRU layer 0
  prep_b<<<3, 256, 0, stream>>>(bih0, bhh0, B2);
  gemm_k<GF_BIAS | GF_BT><<<rt * 12, 256, 0, stream>>>(X, Wih0, B2, GI, N_NODES, 256, G3);
  prep_w<<<384, 256, 0, stream>>>(Whh0, Wpk);
  gru_scan<<<64, 1024, 0, stream>>>(GI, Wpk, bhh0, X);  // H1 overwrites X
  // GRU layer 1
  prep_b<<<3, 256, 0, stream>>>(bih1, bhh1, B2);
  gemm_k<GF_BIAS | GF_BT><<<rt * 12, 256, 0, stream>>>(X, Wih1, B2, GI, N_NODES, 256, G3);
  prep_w<<<384, 256, 0, stream>>>(Whh1, Wpk);
  gru_scan<<<64, 1024, 0, stream>>>(GI, Wpk, bhh1, H2);
  // CSR build
  hipMemsetAsync(DEG, 0, N_NODES * 4, stream);
  hipMemsetAsync(CNT, 0, N_NODES * 4, stream);
  deg_k<<<2500, 256, 0, stream>>>(ei, DEG);
  scan_k<<<1, 1024, 0, stream>>>(DEG, OFF);
  scatter_k<<<2500, 256, 0, stream>>>(ei, OFF, CNT, CSR);
  // GAT layer 1
  gemm_k<GF_RELU_A><<<rt * 2, 256, 0, stream>>>(H2, Wg1, nullptr, HGa, N_NODES, 256, HC);
  esed_k<<<625, 256, 0, stream>>>(HGa, as1, ad1, ES, ED);
  hipMemsetAsync(ESM, 0, 8 * 4, stream);
  esmax_k<<<625, 256, 0, stream>>>(ES, ESM);
  gather_k<1><<<5000, 256, 0, stream>>>(OFF, CSR, ES, ED, ESM, HGa, bg1, X2);
  // GAT layer 2
  gemm_k<0><<<rt * 2, 256, 0, stream>>>(X2, Wg2, nullptr, HGa, N_NODES, HC, HC);
  esed_k<<<625, 256, 0, stream>>>(HGa, as2, ad2, ES, ED);
  hipMemsetAsync(ESM, 0, 8 * 4, stream);
  esmax_k<<<625, 256, 0, stream>>>(ES, ESM);
  gather_k<0><<<5000, 256, 0, stream>>>(OFF, CSR, ES, ED, ESM, HGa, nullptr, HGb);
  // heads
  heads_k<<<N_NODES, 64, 0, stream>>>(HGb, bg2, H2, Wc, bc, Wmu, bmu, Wm, bm, out);
}